// Round 3
// baseline (704.738 us; speedup 1.0000x reference)
//
#include <hip/hip_runtime.h>
#include <hip/hip_cooperative_groups.h>
#include <math.h>

namespace cg = cooperative_groups;

// ---------------------------------------------------------------------------
// AdderNet LeNet forward. R17: cooperative mega-kernel (R16 + compile fix:
// fallback used `out` instead of `outp`).
// Theory: the 6-dispatch chain carries ~90us launch/serialization overhead;
// fuse all stages into ONE cooperative dispatch with 4 grid.sync()s.
//   - __launch_bounds__(256, 2): VGPR<=256 => 2 blocks/CU => 512 blocks fit.
//   - Launch error checked; falls back to proven R14 6-dispatch path.
//   - BN partials via deterministic per-virtual-block writes (no zero-init,
//     no atomic ordering races inside the single dispatch).
// ---------------------------------------------------------------------------

#define B_N 128
#define EPSBN 1e-5f
#define NBLK 512
#define NCOPY 16

// ============================ mega kernel ==================================
__global__ __launch_bounds__(256, 2) void mega_kernel(
    const float* __restrict__ x, const float* __restrict__ w1,
    const float* __restrict__ g1, const float* __restrict__ be1,
    const float* __restrict__ w2, const float* __restrict__ g2,
    const float* __restrict__ be2, const float* __restrict__ fw1,
    const float* __restrict__ fb1, const float* __restrict__ fw2,
    const float* __restrict__ fb2, float* __restrict__ out,
    float* __restrict__ ws) {
  // workspace layout (floats) — all disjoint
  float* h1     = ws;                // 1,474,560   [128][20][24][24]
  float* h2     = ws + 1480000;      // 409,600     [128][50][8][8]
  float* w2t    = ws + 1900000;      // 32,000      [20][25][64]
  float* sums1p = ws + 1940000;      // 28,800      [720][40] per-vblock
  float* sums2p = ws + 1970000;      // 51,200      [512][100] per-block
  float* featT4 = ws + 2030000;      // 102,400     [200][128][4]
  float* hid    = ws + 2140000;      // 65,536      [128][512]

  __shared__ float smem[1664];       // 6656 B: lh[1440] | sb[40] | csum[100]
  const int tid = threadIdx.x;
  const int bk  = blockIdx.x;
  cg::grid_group grid = cg::this_grid();

  // ============ S1: w2t transpose + adder1 + BN1 per-vblock partials =======
  {
    int i = bk * 256 + tid;
    if (i < 32000) {
      int o = i & 63, t = i >> 6, k = t % 25, c = t / 25;
      w2t[i] = (o < 50) ? w2[o * 500 + c * 25 + k] : 0.f;
    }
  }
  for (int vb = bk; vb < 720; vb += NBLK) {   // 720 vblocks over 512 blocks
    if (tid < 40) smem[tid] = 0.f;
    __syncthreads();
    int idx = vb * 256 + tid;
    int owc = idx % 3; int t = idx / 3;
    int oh  = t % 24;  t /= 24;
    int o   = t % 20;  int b = t / 20;
    const float* xb = x + b * 784;
    const float* wb = w1 + o * 25;
    float acc[8];
#pragma unroll
    for (int i2 = 0; i2 < 8; ++i2) acc[i2] = 0.f;
#pragma unroll
    for (int kh = 0; kh < 5; ++kh) {
      float xr[12];
      const float4* xp = (const float4*)(xb + (oh + kh) * 28 + owc * 8);
#pragma unroll
      for (int i2 = 0; i2 < 3; ++i2) {
        float4 v = xp[i2];
        xr[4*i2] = v.x; xr[4*i2+1] = v.y; xr[4*i2+2] = v.z; xr[4*i2+3] = v.w;
      }
      float wr[5];
#pragma unroll
      for (int i2 = 0; i2 < 5; ++i2) wr[i2] = wb[kh * 5 + i2];
#pragma unroll
      for (int ow = 0; ow < 8; ++ow)
#pragma unroll
        for (int kw = 0; kw < 5; ++kw)
          acc[ow] += fabsf(xr[ow + kw] - wr[kw]);
    }
    float* op = h1 + (((size_t)b * 20 + o) * 24 + oh) * 24 + owc * 8;
    float4 s0v = { -acc[0], -acc[1], -acc[2], -acc[3] };
    float4 s1v = { -acc[4], -acc[5], -acc[6], -acc[7] };
    *(float4*)(op)     = s0v;
    *(float4*)(op + 4) = s1v;
    float s = 0.f, s2 = 0.f;
#pragma unroll
    for (int i2 = 0; i2 < 8; ++i2) { s -= acc[i2]; s2 += acc[i2] * acc[i2]; }
    atomicAdd(&smem[o * 2],     s);
    atomicAdd(&smem[o * 2 + 1], s2);
    __syncthreads();
    if (tid < 40) sums1p[vb * 40 + tid] = smem[tid];
    // cross-iteration smem reuse is safe: only tid<40 writes both the
    // sums1p flush and the re-zero (program order); all other threads sit
    // at the next __syncthreads before any atomicAdd.
  }
  __threadfence();
  grid.sync();
  __threadfence();

  // ============ S2: BN1 finalize + stage/pool + adder2 + BN2 partials ======
  {
    float p = 0.f;
    if (tid < 240) {                         // 40 stats x 6 chunks of 120 vbs
      int sv = tid % 40, ch = tid / 40;
      const float* sp = sums1p + (ch * 120) * 40 + sv;
#pragma unroll 8
      for (int i = 0; i < 120; ++i) p += sp[i * 40];
    }
    if (tid < 240) smem[tid] = p;
    __syncthreads();
    if (tid < 40) {
      float sm = smem[tid] + smem[tid + 40] + smem[tid + 80] +
                 smem[tid + 120] + smem[tid + 160] + smem[tid + 200];
      smem[1440 + tid] = sm;
    }
    __syncthreads();
    if (tid < 20) {
      const float inv_n = 1.f / (B_N * 576);
      float mean = smem[1440 + 2 * tid] * inv_n;
      float var  = smem[1440 + 2 * tid + 1] * inv_n - mean * mean;
      float sc   = g1[tid] * rsqrtf(var + EPSBN);
      smem[1440 + 2 * tid]     = sc;
      smem[1440 + 2 * tid + 1] = be1[tid] - mean * sc;
    }
    if (tid < 100) smem[1480 + tid] = 0.f;   // csum2
    __syncthreads();
  }
  const int oq = bk & 3;
  const int bb = bk >> 2;                    // 512 blocks = 128 b x 4 oq
  {
    const float* hb = h1 + (size_t)bb * 11520;
    for (int j = tid; j < 1440; j += 256) {  // lh[c][6 rows][12]
      int c = j / 72, rem = j - c * 72;
      int r = rem / 12, col = rem - r * 12;
      const float* hp = hb + (c * 24 + (4 * oq + 2 * r)) * 24 + 2 * col;
      float2 r0 = *(const float2*)(hp);
      float2 r1 = *(const float2*)(hp + 24);
      float sc = smem[1440 + 2 * c], bi = smem[1440 + 2 * c + 1];
      float v0 = fmaf(sc, r0.x, bi);
      float v1 = fmaf(sc, r0.y, bi);
      float v2 = fmaf(sc, r1.x, bi);
      float v3 = fmaf(sc, r1.y, bi);
      smem[j] = fmaxf(fmaxf(v0, v1), fmaxf(v2, v3));
    }
  }
  __syncthreads();
  {
    const int o   = tid >> 2;
    const int q   = tid & 3;
    const int ohl = q >> 1;
    const int owh = q & 1;
    if (o < 50) {
      float acc2[4];
#pragma unroll
      for (int i = 0; i < 4; ++i) acc2[i] = 0.f;
      for (int c = 0; c < 20; ++c) {
        const float* lc = smem + c * 72 + owh * 4;
        const float* wc = w2t + c * 1600 + o;
#pragma unroll
        for (int kh = 0; kh < 5; ++kh) {
          float hr[8];
          const float* lp = lc + (ohl + kh) * 12;
          *(float4*)(hr)     = *(const float4*)(lp);
          *(float4*)(hr + 4) = *(const float4*)(lp + 4);
          float wr2[5];
#pragma unroll
          for (int i = 0; i < 5; ++i) wr2[i] = wc[(kh * 5 + i) * 64];
#pragma unroll
          for (int ow = 0; ow < 4; ++ow)
#pragma unroll
            for (int kw = 0; kw < 5; ++kw)
              acc2[ow] += fabsf(hr[ow + kw] - wr2[kw]);
        }
      }
      const int oh2 = 2 * oq + ohl;
      float4 st = { -acc2[0], -acc2[1], -acc2[2], -acc2[3] };
      *(float4*)(h2 + (((size_t)bb * 50 + o) * 8 + oh2) * 8 + owh * 4) = st;
      float s = 0.f, s2 = 0.f;
#pragma unroll
      for (int i = 0; i < 4; ++i) { s -= acc2[i]; s2 += acc2[i] * acc2[i]; }
      atomicAdd(&smem[1480 + o * 2],     s);
      atomicAdd(&smem[1480 + o * 2 + 1], s2);
    }
  }
  __syncthreads();
  if (tid < 100) sums2p[bk * 100 + tid] = smem[1480 + tid];
  __threadfence();
  grid.sync();
  __threadfence();

  // ============ S3: BN2 finalize + apply + 2x2 maxpool -> featT4 ===========
  if (bk < 400) {
    float p = 0.f;
    if (tid < 200) {                         // 100 stats x 2 chunks of 256
      int sv = tid % 100, ch = tid / 100;
      const float* sp = sums2p + (ch * 256) * 100 + sv;
#pragma unroll 8
      for (int i = 0; i < 256; ++i) p += sp[i * 100];
    }
    if (tid < 200) smem[tid] = p;
    __syncthreads();
    if (tid < 100) smem[1440 + tid] = smem[tid] + smem[tid + 100];
    __syncthreads();
    if (tid < 50) {
      const float inv_n = 1.f / (B_N * 64);
      float mean = smem[1440 + 2 * tid] * inv_n;
      float var  = smem[1440 + 2 * tid + 1] * inv_n - mean * mean;
      float sc   = g2[tid] * rsqrtf(var + EPSBN);
      smem[1440 + 2 * tid]     = sc;
      smem[1440 + 2 * tid + 1] = be2[tid] - mean * sc;
    }
    __syncthreads();
    int idx = bk * 256 + tid;                // 102400 = 400*256
    int pw = idx % 4; int t = idx / 4;
    int ph = t % 4;   t /= 4;
    int c  = t % 50;  int b = t / 50;
    float sc = smem[1440 + 2 * c], bi = smem[1440 + 2 * c + 1];
    const float* hp = h2 + ((b * 50 + c) * 8 + 2 * ph) * 8 + 2 * pw;
    float2 r0 = *(const float2*)(hp);
    float2 r1 = *(const float2*)(hp + 8);
    float v0 = fmaf(sc, r0.x, bi);
    float v1 = fmaf(sc, r0.y, bi);
    float v2 = fmaf(sc, r1.x, bi);
    float v3 = fmaf(sc, r1.y, bi);
    int kq = c * 4 + ph;
    featT4[(kq * 128 + b) * 4 + pw] = fmaxf(fmaxf(v0, v1), fmaxf(v2, v3));
  }
  __threadfence();
  grid.sync();
  __threadfence();

  // ============ S4: fc1 + relu ============================================
  if (bk < 500) {
    const int j = bk;
    const int b = tid & 127;
    const int khalf = tid >> 7;
    const float* wr = fw1 + j * 800;
    float a0 = 0.f, a1 = 0.f, a2 = 0.f, a3 = 0.f;
    int q0 = khalf * 100;
    for (int qi = q0; qi < q0 + 100; ++qi) {
      float4 f  = *(const float4*)(featT4 + (size_t)(qi * 128 + b) * 4);
      float4 w4 = *(const float4*)(wr + qi * 4);   // wave-uniform
      a0 = fmaf(f.x, w4.x, a0);
      a1 = fmaf(f.y, w4.y, a1);
      a2 = fmaf(f.z, w4.z, a2);
      a3 = fmaf(f.w, w4.w, a3);
    }
    smem[tid] = (a0 + a1) + (a2 + a3);
    __syncthreads();
    if (tid < 128)
      hid[b * 512 + j] = fmaxf(fb1[j] + smem[tid] + smem[tid + 128], 0.f);
  }
  __threadfence();
  grid.sync();
  __threadfence();

  // ============ S5: fc2 + softmax (one wave per batch row) ================
  if (bk < 128 && tid < 64) {
    const int b = bk, lane = tid;
    const float* hb = hid + b * 512;
    float hv[8];
#pragma unroll
    for (int i = 0; i < 8; ++i) {
      int k = lane + 64 * i;
      hv[i] = (k < 500) ? hb[k] : 0.f;
    }
    float lg[10];
#pragma unroll
    for (int j = 0; j < 10; ++j) {
      const float* wr = fw2 + j * 500;
      float acc = 0.f;
#pragma unroll
      for (int i = 0; i < 8; ++i) {
        int k = lane + 64 * i;
        float w = (k < 500) ? wr[k] : 0.f;
        acc = fmaf(hv[i], w, acc);
      }
#pragma unroll
      for (int off = 32; off > 0; off >>= 1) acc += __shfl_down(acc, off);
      lg[j] = acc + fb2[j];                  // valid at lane 0
    }
    if (lane == 0) {
      float m = lg[0];
#pragma unroll
      for (int j = 1; j < 10; ++j) m = fmaxf(m, lg[j]);
      float s = 0.f, e[10];
#pragma unroll
      for (int j = 0; j < 10; ++j) { e[j] = __expf(lg[j] - m); s += e[j]; }
      float inv = 1.f / s;
#pragma unroll
      for (int j = 0; j < 10; ++j) out[b * 10 + j] = e[j] * inv;
    }
  }
}

// ======================= R14 fallback kernels ==============================
__global__ __launch_bounds__(256) void prep_kernel(
    const float* __restrict__ w2, float* __restrict__ w2t,
    float* __restrict__ sums) {
  int idx = blockIdx.x * 256 + threadIdx.x;   // 134*256 = 34304
  if (idx < 32000) {
    int o = idx & 63, t = idx >> 6, k = t % 25, c = t / 25;
    w2t[idx] = (o < 50) ? w2[o * 500 + c * 25 + k] : 0.f;
  } else {
    int j = idx - 32000;
    if (j < NCOPY * 140) sums[j] = 0.f;
  }
}

__global__ __launch_bounds__(256) void adder1_bn_kernel(
    const float* __restrict__ x, const float* __restrict__ w1,
    float* __restrict__ out, float* __restrict__ sums) {
  __shared__ float csum[40];
  if (threadIdx.x < 40) csum[threadIdx.x] = 0.f;
  __syncthreads();
  int idx = blockIdx.x * 256 + threadIdx.x;
  int owc = idx % 3; int t = idx / 3;
  int oh  = t % 24;  t /= 24;
  int o   = t % 20;  int b = t / 20;
  const float* xb = x + b * 784;
  const float* wb = w1 + o * 25;
  float acc[8];
#pragma unroll
  for (int i = 0; i < 8; ++i) acc[i] = 0.f;
#pragma unroll
  for (int kh = 0; kh < 5; ++kh) {
    float xr[12];
    const float4* xp = (const float4*)(xb + (oh + kh) * 28 + owc * 8);
#pragma unroll
    for (int i = 0; i < 3; ++i) {
      float4 v = xp[i];
      xr[4*i] = v.x; xr[4*i+1] = v.y; xr[4*i+2] = v.z; xr[4*i+3] = v.w;
    }
    float wr[5];
#pragma unroll
    for (int i = 0; i < 5; ++i) wr[i] = wb[kh * 5 + i];
#pragma unroll
    for (int ow = 0; ow < 8; ++ow)
#pragma unroll
      for (int kw = 0; kw < 5; ++kw)
        acc[ow] += fabsf(xr[ow + kw] - wr[kw]);
  }
  float* op = out + (((size_t)b * 20 + o) * 24 + oh) * 24 + owc * 8;
  float4 s0 = { -acc[0], -acc[1], -acc[2], -acc[3] };
  float4 s1 = { -acc[4], -acc[5], -acc[6], -acc[7] };
  *(float4*)(op)     = s0;
  *(float4*)(op + 4) = s1;
  float s = 0.f, s2 = 0.f;
#pragma unroll
  for (int i = 0; i < 8; ++i) { s -= acc[i]; s2 += acc[i] * acc[i]; }
  atomicAdd(&csum[o * 2],     s);
  atomicAdd(&csum[o * 2 + 1], s2);
  __syncthreads();
  if (threadIdx.x < 40) {
    float v = csum[threadIdx.x];
    if (v != 0.f)
      atomicAdd(&sums[(blockIdx.x & (NCOPY - 1)) * 40 + threadIdx.x], v);
  }
}

__global__ __launch_bounds__(256) void adder2_bn_kernel(
    const float* __restrict__ h1, const float* __restrict__ sums1,
    const float* __restrict__ g1, const float* __restrict__ be1,
    const float* __restrict__ w2t,
    float* __restrict__ out, float* __restrict__ sums2) {
  __shared__ float lh[1440];
  __shared__ float sb[40];
  __shared__ float csum[100];
  const int tid = threadIdx.x;
  if (tid < 100) csum[tid] = 0.f;
  if (tid < 20) {
    float sm = 0.f, s2 = 0.f;
#pragma unroll
    for (int cp = 0; cp < NCOPY; ++cp) {
      sm += sums1[cp * 40 + 2 * tid];
      s2 += sums1[cp * 40 + 2 * tid + 1];
    }
    const float inv_n = 1.f / (B_N * 576);
    float mean = sm * inv_n;
    float var  = s2 * inv_n - mean * mean;
    float sc   = g1[tid] * rsqrtf(var + EPSBN);
    sb[2 * tid]     = sc;
    sb[2 * tid + 1] = be1[tid] - mean * sc;
  }
  __syncthreads();
  const int oq = blockIdx.x & 3;
  const int b  = blockIdx.x >> 2;
  {
    const float* hb = h1 + (size_t)b * 11520;
    for (int j = tid; j < 1440; j += 256) {
      int c = j / 72, rem = j - c * 72;
      int r = rem / 12, col = rem - r * 12;
      const float* hp = hb + (c * 24 + (4 * oq + 2 * r)) * 24 + 2 * col;
      float2 r0 = *(const float2*)(hp);
      float2 r1 = *(const float2*)(hp + 24);
      float sc = sb[2 * c], bi = sb[2 * c + 1];
      float v0 = fmaf(sc, r0.x, bi);
      float v1 = fmaf(sc, r0.y, bi);
      float v2 = fmaf(sc, r1.x, bi);
      float v3 = fmaf(sc, r1.y, bi);
      lh[j] = fmaxf(fmaxf(v0, v1), fmaxf(v2, v3));
    }
  }
  __syncthreads();
  const int o   = tid >> 2;
  const int q   = tid & 3;
  const int ohl = q >> 1;
  const int owh = q & 1;
  if (o < 50) {
    float acc[4];
#pragma unroll
    for (int i = 0; i < 4; ++i) acc[i] = 0.f;
    for (int c = 0; c < 20; ++c) {
      const float* lc = lh + c * 72 + owh * 4;
      const float* wc = w2t + c * 1600 + o;
#pragma unroll
      for (int kh = 0; kh < 5; ++kh) {
        float hr[8];
        const float* lp = lc + (ohl + kh) * 12;
        *(float4*)(hr)     = *(const float4*)(lp);
        *(float4*)(hr + 4) = *(const float4*)(lp + 4);
        float wr[5];
#pragma unroll
        for (int i = 0; i < 5; ++i) wr[i] = wc[(kh * 5 + i) * 64];
#pragma unroll
        for (int ow = 0; ow < 4; ++ow)
#pragma unroll
          for (int kw = 0; kw < 5; ++kw)
            acc[ow] += fabsf(hr[ow + kw] - wr[kw]);
      }
    }
    const int oh = 2 * oq + ohl;
    float4 st = { -acc[0], -acc[1], -acc[2], -acc[3] };
    *(float4*)(out + (((size_t)b * 50 + o) * 8 + oh) * 8 + owh * 4) = st;
    float s = 0.f, s2 = 0.f;
#pragma unroll
    for (int i = 0; i < 4; ++i) { s -= acc[i]; s2 += acc[i] * acc[i]; }
    atomicAdd(&csum[o * 2],     s);
    atomicAdd(&csum[o * 2 + 1], s2);
  }
  __syncthreads();
  if (tid < 100)
    atomicAdd(&sums2[(blockIdx.x & (NCOPY - 1)) * 100 + tid], csum[tid]);
}

__global__ __launch_bounds__(256) void bn_pool_t_kernel(
    const float* __restrict__ h, const float* __restrict__ sums,
    const float* __restrict__ gamma, const float* __restrict__ beta,
    float* __restrict__ featT4, float inv_n) {
  int idx = blockIdx.x * 256 + threadIdx.x;
  int pw = idx % 4; int t = idx / 4;
  int ph = t % 4;   t /= 4;
  int c  = t % 50;  int b = t / 50;
  float sm = 0.f, s2 = 0.f;
#pragma unroll
  for (int cp = 0; cp < NCOPY; ++cp) {
    sm += sums[cp * 100 + 2 * c];
    s2 += sums[cp * 100 + 2 * c + 1];
  }
  float mean = sm * inv_n;
  float var  = s2 * inv_n - mean * mean;
  float sc   = gamma[c] * rsqrtf(var + EPSBN);
  float bi   = beta[c] - mean * sc;
  const float* hp = h + ((b * 50 + c) * 8 + 2 * ph) * 8 + 2 * pw;
  float2 r0 = *(const float2*)(hp);
  float2 r1 = *(const float2*)(hp + 8);
  float v0 = fmaf(sc, r0.x, bi);
  float v1 = fmaf(sc, r0.y, bi);
  float v2 = fmaf(sc, r1.x, bi);
  float v3 = fmaf(sc, r1.y, bi);
  int kq = c * 4 + ph;
  featT4[(kq * 128 + b) * 4 + pw] = fmaxf(fmaxf(v0, v1), fmaxf(v2, v3));
}

__global__ __launch_bounds__(256) void fc1_kernel(
    const float* __restrict__ featT4, const float* __restrict__ w1,
    const float* __restrict__ b1, float* __restrict__ hid) {
  const int j = blockIdx.x;
  const int b = threadIdx.x & 127;
  const int khalf = threadIdx.x >> 7;
  const float* wr = w1 + j * 800;
  float a0 = 0.f, a1 = 0.f, a2 = 0.f, a3 = 0.f;
  int q0 = khalf * 100;
  for (int qi = q0; qi < q0 + 100; ++qi) {
    float4 f  = *(const float4*)(featT4 + (size_t)(qi * 128 + b) * 4);
    float4 w4 = *(const float4*)(wr + qi * 4);
    a0 = fmaf(f.x, w4.x, a0);
    a1 = fmaf(f.y, w4.y, a1);
    a2 = fmaf(f.z, w4.z, a2);
    a3 = fmaf(f.w, w4.w, a3);
  }
  __shared__ float part[256];
  part[threadIdx.x] = (a0 + a1) + (a2 + a3);
  __syncthreads();
  if (threadIdx.x < 128)
    hid[b * 512 + j] =
        fmaxf(b1[j] + part[threadIdx.x] + part[threadIdx.x + 128], 0.f);
}

__global__ __launch_bounds__(64) void fc2_softmax_kernel(
    const float* __restrict__ hid, const float* __restrict__ w2,
    const float* __restrict__ b2, float* __restrict__ out) {
  const int b = blockIdx.x, lane = threadIdx.x;
  const float* hb = hid + b * 512;
  __shared__ float logit[16];
  float hv[8];
#pragma unroll
  for (int i = 0; i < 8; ++i) {
    int k = lane + 64 * i;
    hv[i] = (k < 500) ? hb[k] : 0.f;
  }
  for (int j = 0; j < 10; ++j) {
    const float* wr = w2 + j * 500;
    float acc = 0.f;
#pragma unroll
    for (int i = 0; i < 8; ++i) {
      int k = lane + 64 * i;
      float w = (k < 500) ? wr[k] : 0.f;
      acc = fmaf(hv[i], w, acc);
    }
#pragma unroll
    for (int off = 32; off > 0; off >>= 1) acc += __shfl_down(acc, off);
    if (lane == 0) logit[j] = acc + b2[j];
  }
  __syncthreads();
  if (lane == 0) {
    float m = logit[0];
    for (int j = 1; j < 10; ++j) m = fmaxf(m, logit[j]);
    float s = 0.f, e[10];
    for (int j = 0; j < 10; ++j) { e[j] = __expf(logit[j] - m); s += e[j]; }
    float inv = 1.f / s;
    for (int j = 0; j < 10; ++j) out[b * 10 + j] = e[j] * inv;
  }
}

extern "C" void kernel_launch(void* const* d_in, const int* in_sizes, int n_in,
                              void* d_out, int out_size, void* d_ws, size_t ws_size,
                              hipStream_t stream) {
  const float* x   = (const float*)d_in[0];   // [128,1,28,28]
  const float* w1  = (const float*)d_in[1];   // [20,1,5,5]
  const float* g1  = (const float*)d_in[2];   // [20]
  const float* be1 = (const float*)d_in[3];   // [20]
  const float* w2  = (const float*)d_in[4];   // [50,20,5,5]
  const float* g2  = (const float*)d_in[5];   // [50]
  const float* be2 = (const float*)d_in[6];   // [50]
  const float* fw1 = (const float*)d_in[7];   // [500,800]
  const float* fb1 = (const float*)d_in[8];   // [500]
  const float* fw2 = (const float*)d_in[9];   // [10,500]
  const float* fb2 = (const float*)d_in[10];  // [10]
  float* outp = (float*)d_out;
  float* ws   = (float*)d_ws;

  void* args[13] = {(void*)&x,   (void*)&w1,  (void*)&g1,  (void*)&be1,
                    (void*)&w2,  (void*)&g2,  (void*)&be2, (void*)&fw1,
                    (void*)&fb1, (void*)&fw2, (void*)&fb2, (void*)&outp,
                    (void*)&ws};
  hipError_t err = hipLaunchCooperativeKernel(
      (const void*)mega_kernel, dim3(NBLK), dim3(256), args, 0, stream);

  if (err != hipSuccess) {
    // ---- fallback: proven R14 6-dispatch path (own ws sub-layout) ----
    float* h1     = ws;               // 1,474,560
    float* sums1  = ws + 1843200;     // 640
    float* sums2  = ws + 1843840;     // 1600
    float* w2t    = ws + 1845504;     // 32,000
    float* h2     = ws + 1900000;     // 409,600
    float* featT4 = ws + 2310000;     // 102,400
    float* hid    = ws + 2420000;     // 65,536
    prep_kernel<<<134, 256, 0, stream>>>(w2, w2t, sums1);
    adder1_bn_kernel<<<720, 256, 0, stream>>>(x, w1, h1, sums1);
    adder2_bn_kernel<<<512, 256, 0, stream>>>(h1, sums1, g1, be1, w2t, h2, sums2);
    bn_pool_t_kernel<<<400, 256, 0, stream>>>(h2, sums2, g2, be2, featT4,
                                              1.f / (B_N * 64));
    fc1_kernel<<<500, 256, 0, stream>>>(featT4, fw1, fb1, hid);
    fc2_softmax_kernel<<<128, 64, 0, stream>>>(hid, fw2, fb2, outp);
  }
}

// Round 4
// 505.467 us; speedup vs baseline: 1.3942x; 1.3942x over previous
//
#include <hip/hip_runtime.h>
#include <math.h>

// ---------------------------------------------------------------------------
// AdderNet LeNet forward. R18: cooperative mega-kernel with HAND-ROLLED grid
// barrier. R17 measured cg::grid_group::sync() at ~145us each (623us total,
// VALUBusy 4%) — the ROCm CG spin loop invalidates L2 per poll. Replace with
// one-shot per-phase counters: release-fence + relaxed atomicAdd + RELAXED
// polling + single acquire-fence on exit (~5us/barrier predicted).
// Also: 720 blocks (no S1 loop), transposed BN-partial layouts
// (sums1p[40][720], sums2p[100][512]) for contiguous float4 reductions.
// Counters zeroed by hipMemsetAsync(512B) before the launch (capturable).
// Fallback to proven R14 6-dispatch path on any launch error.
// ---------------------------------------------------------------------------

#define B_N 128
#define EPSBN 1e-5f
#define NBLK 720
#define NCOPY 16

__device__ __forceinline__ void grid_barrier(unsigned* cnt, unsigned nblk) {
  __syncthreads();
  if (threadIdx.x == 0) {
    __threadfence();   // release: write back this XCD's dirty L2 to IF
    __hip_atomic_fetch_add(cnt, 1u, __ATOMIC_RELAXED,
                           __HIP_MEMORY_SCOPE_AGENT);
    while (__hip_atomic_load(cnt, __ATOMIC_RELAXED,
                             __HIP_MEMORY_SCOPE_AGENT) < nblk)
      __builtin_amdgcn_s_sleep(16);      // ~430ns backoff, no inv per poll
    __threadfence();   // acquire: invalidate L1/L2 so stage reads are fresh
  }
  __syncthreads();
}

// ============================ mega kernel ==================================
__global__ __launch_bounds__(256, 3) void mega_kernel(
    const float* __restrict__ x, const float* __restrict__ w1,
    const float* __restrict__ g1, const float* __restrict__ be1,
    const float* __restrict__ w2, const float* __restrict__ g2,
    const float* __restrict__ be2, const float* __restrict__ fw1,
    const float* __restrict__ fb1, const float* __restrict__ fw2,
    const float* __restrict__ fb2, float* __restrict__ out,
    float* __restrict__ ws) {
  // workspace layout (floats) — all disjoint
  float* h1     = ws;                // 1,474,560   [128][20][24][24]
  float* h2     = ws + 1480000;      // 409,600     [128][50][8][8]
  float* w2t    = ws + 1900000;      // 32,000      [20][25][64]
  float* sums1p = ws + 1940000;      // 28,800      [40][720] (transposed)
  float* sums2p = ws + 1970000;      // 51,200      [100][512] (transposed)
  float* featT4 = ws + 2030000;      // 102,400     [200][128][4]
  float* hid    = ws + 2140000;      // 65,536      [128][512]
  unsigned* bar = (unsigned*)(ws + 2600000);  // 4 one-shot counters, 128B apart

  __shared__ float smem[1664];       // 6656 B: lh[1440] | sb[40] | csum[100]
  const int tid = threadIdx.x;
  const int bk  = blockIdx.x;

  // ============ S1: w2t transpose + adder1 + BN1 per-block partials ========
  if (tid < 40) smem[tid] = 0.f;
  {
    int i = bk * 256 + tid;
    if (i < 32000) {
      int o = i & 63, t = i >> 6, k = t % 25, c = t / 25;
      w2t[i] = (o < 50) ? w2[o * 500 + c * 25 + k] : 0.f;
    }
  }
  __syncthreads();
  {
    int idx = bk * 256 + tid;        // 184320 = 720*256, exact
    int owc = idx % 3; int t = idx / 3;
    int oh  = t % 24;  t /= 24;
    int o   = t % 20;  int b = t / 20;
    const float* xb = x + b * 784;
    const float* wb = w1 + o * 25;
    float acc[8];
#pragma unroll
    for (int i2 = 0; i2 < 8; ++i2) acc[i2] = 0.f;
#pragma unroll
    for (int kh = 0; kh < 5; ++kh) {
      float xr[12];
      const float4* xp = (const float4*)(xb + (oh + kh) * 28 + owc * 8);
#pragma unroll
      for (int i2 = 0; i2 < 3; ++i2) {
        float4 v = xp[i2];
        xr[4*i2] = v.x; xr[4*i2+1] = v.y; xr[4*i2+2] = v.z; xr[4*i2+3] = v.w;
      }
      float wr[5];
#pragma unroll
      for (int i2 = 0; i2 < 5; ++i2) wr[i2] = wb[kh * 5 + i2];
#pragma unroll
      for (int ow = 0; ow < 8; ++ow)
#pragma unroll
        for (int kw = 0; kw < 5; ++kw)
          acc[ow] += fabsf(xr[ow + kw] - wr[kw]);
    }
    float* op = h1 + (((size_t)b * 20 + o) * 24 + oh) * 24 + owc * 8;
    float4 s0v = { -acc[0], -acc[1], -acc[2], -acc[3] };
    float4 s1v = { -acc[4], -acc[5], -acc[6], -acc[7] };
    *(float4*)(op)     = s0v;
    *(float4*)(op + 4) = s1v;
    float s = 0.f, s2 = 0.f;
#pragma unroll
    for (int i2 = 0; i2 < 8; ++i2) { s -= acc[i2]; s2 += acc[i2] * acc[i2]; }
    atomicAdd(&smem[o * 2],     s);
    atomicAdd(&smem[o * 2 + 1], s2);
  }
  __syncthreads();
  if (tid < 40) sums1p[tid * 720 + bk] = smem[tid];   // [40][720]
  grid_barrier(bar + 0, NBLK);

  // ============ S2: BN1 finalize + stage/pool + adder2 + BN2 partials ======
  if (bk < 512) {
    {
      // redundant per-block reduction: sums1p[40][720], contiguous float4
      float p = 0.f;
      if (tid < 240) {                      // 40 stats x 6 chunks of 120
        int sv = tid / 6, ch = tid % 6;
        const float4* sp = (const float4*)(sums1p + sv * 720 + ch * 120);
#pragma unroll
        for (int i = 0; i < 30; ++i) {
          float4 v = sp[i];
          p += (v.x + v.y) + (v.z + v.w);
        }
        smem[tid] = p;
      }
      __syncthreads();
      if (tid < 40) {
        float sm = 0.f;
#pragma unroll
        for (int i = 0; i < 6; ++i) sm += smem[tid * 6 + i];
        smem[1440 + tid] = sm;
      }
      __syncthreads();
      if (tid < 20) {
        const float inv_n = 1.f / (B_N * 576);
        float mean = smem[1440 + 2 * tid] * inv_n;
        float var  = smem[1440 + 2 * tid + 1] * inv_n - mean * mean;
        float sc   = g1[tid] * rsqrtf(var + EPSBN);
        smem[1440 + 2 * tid]     = sc;
        smem[1440 + 2 * tid + 1] = be1[tid] - mean * sc;
      }
      if (tid < 100) smem[1480 + tid] = 0.f;   // csum2
      __syncthreads();
    }
    const int oq = bk & 3;
    const int bb = bk >> 2;                  // 512 = 128 b x 4 oq
    {
      const float* hb = h1 + (size_t)bb * 11520;
      for (int j = tid; j < 1440; j += 256) {  // lh[c][6 rows][12]
        int c = j / 72, rem = j - c * 72;
        int r = rem / 12, col = rem - r * 12;
        const float* hp = hb + (c * 24 + (4 * oq + 2 * r)) * 24 + 2 * col;
        float2 r0 = *(const float2*)(hp);
        float2 r1 = *(const float2*)(hp + 24);
        float sc = smem[1440 + 2 * c], bi = smem[1440 + 2 * c + 1];
        float v0 = fmaf(sc, r0.x, bi);
        float v1 = fmaf(sc, r0.y, bi);
        float v2 = fmaf(sc, r1.x, bi);
        float v3 = fmaf(sc, r1.y, bi);
        smem[j] = fmaxf(fmaxf(v0, v1), fmaxf(v2, v3));
      }
    }
    __syncthreads();
    {
      const int o   = tid >> 2;
      const int q   = tid & 3;
      const int ohl = q >> 1;
      const int owh = q & 1;
      if (o < 50) {
        float acc2[4];
#pragma unroll
        for (int i = 0; i < 4; ++i) acc2[i] = 0.f;
        for (int c = 0; c < 20; ++c) {
          const float* lc = smem + c * 72 + owh * 4;
          const float* wc = w2t + c * 1600 + o;
#pragma unroll
          for (int kh = 0; kh < 5; ++kh) {
            float hr[8];
            const float* lp = lc + (ohl + kh) * 12;
            *(float4*)(hr)     = *(const float4*)(lp);
            *(float4*)(hr + 4) = *(const float4*)(lp + 4);
            float wr2[5];
#pragma unroll
            for (int i = 0; i < 5; ++i) wr2[i] = wc[(kh * 5 + i) * 64];
#pragma unroll
            for (int ow = 0; ow < 4; ++ow)
#pragma unroll
              for (int kw = 0; kw < 5; ++kw)
                acc2[ow] += fabsf(hr[ow + kw] - wr2[kw]);
          }
        }
        const int oh2 = 2 * oq + ohl;
        float4 st = { -acc2[0], -acc2[1], -acc2[2], -acc2[3] };
        *(float4*)(h2 + (((size_t)bb * 50 + o) * 8 + oh2) * 8 + owh * 4) = st;
        float s = 0.f, s2 = 0.f;
#pragma unroll
        for (int i = 0; i < 4; ++i) { s -= acc2[i]; s2 += acc2[i] * acc2[i]; }
        atomicAdd(&smem[1480 + o * 2],     s);
        atomicAdd(&smem[1480 + o * 2 + 1], s2);
      }
    }
    __syncthreads();
    if (tid < 100) sums2p[tid * 512 + bk] = smem[1480 + tid];  // [100][512]
  }
  grid_barrier(bar + 32, NBLK);

  // ============ S3: BN2 finalize + apply + 2x2 maxpool -> featT4 ===========
  if (bk < 400) {
    float p = 0.f;
    if (tid < 200) {                      // 100 stats x 2 chunks of 256
      int sv = tid >> 1, h = tid & 1;
      const float4* sp = (const float4*)(sums2p + sv * 512 + h * 256);
#pragma unroll
      for (int i = 0; i < 64; ++i) {
        float4 v = sp[i];
        p += (v.x + v.y) + (v.z + v.w);
      }
      smem[tid] = p;
    }
    __syncthreads();
    if (tid < 100) smem[1440 + tid] = smem[2 * tid] + smem[2 * tid + 1];
    __syncthreads();
    if (tid < 50) {
      const float inv_n = 1.f / (B_N * 64);
      float mean = smem[1440 + 2 * tid] * inv_n;
      float var  = smem[1440 + 2 * tid + 1] * inv_n - mean * mean;
      float sc   = g2[tid] * rsqrtf(var + EPSBN);
      smem[1440 + 2 * tid]     = sc;
      smem[1440 + 2 * tid + 1] = be2[tid] - mean * sc;
    }
    __syncthreads();
    int idx = bk * 256 + tid;                // 102400 = 400*256
    int pw = idx % 4; int t = idx / 4;
    int ph = t % 4;   t /= 4;
    int c  = t % 50;  int b = t / 50;
    float sc = smem[1440 + 2 * c], bi = smem[1440 + 2 * c + 1];
    const float* hp = h2 + ((b * 50 + c) * 8 + 2 * ph) * 8 + 2 * pw;
    float2 r0 = *(const float2*)(hp);
    float2 r1 = *(const float2*)(hp + 8);
    float v0 = fmaf(sc, r0.x, bi);
    float v1 = fmaf(sc, r0.y, bi);
    float v2 = fmaf(sc, r1.x, bi);
    float v3 = fmaf(sc, r1.y, bi);
    int kq = c * 4 + ph;
    featT4[(kq * 128 + b) * 4 + pw] = fmaxf(fmaxf(v0, v1), fmaxf(v2, v3));
  }
  grid_barrier(bar + 64, NBLK);

  // ============ S4: fc1 + relu ============================================
  if (bk < 500) {
    const int j = bk;
    const int b = tid & 127;
    const int khalf = tid >> 7;
    const float* wr = fw1 + j * 800;
    float a0 = 0.f, a1 = 0.f, a2 = 0.f, a3 = 0.f;
    int q0 = khalf * 100;
    for (int qi = q0; qi < q0 + 100; ++qi) {
      float4 f  = *(const float4*)(featT4 + (size_t)(qi * 128 + b) * 4);
      float4 w4 = *(const float4*)(wr + qi * 4);   // wave-uniform
      a0 = fmaf(f.x, w4.x, a0);
      a1 = fmaf(f.y, w4.y, a1);
      a2 = fmaf(f.z, w4.z, a2);
      a3 = fmaf(f.w, w4.w, a3);
    }
    smem[tid] = (a0 + a1) + (a2 + a3);
    __syncthreads();
    if (tid < 128)
      hid[b * 512 + j] = fmaxf(fb1[j] + smem[tid] + smem[tid + 128], 0.f);
  }
  grid_barrier(bar + 96, NBLK);

  // ============ S5: fc2 + softmax (one wave per batch row) ================
  if (bk < 128 && tid < 64) {
    const int b = bk, lane = tid;
    const float* hb = hid + b * 512;
    float hv[8];
#pragma unroll
    for (int i = 0; i < 8; ++i) {
      int k = lane + 64 * i;
      hv[i] = (k < 500) ? hb[k] : 0.f;
    }
    float lg[10];
#pragma unroll
    for (int j = 0; j < 10; ++j) {
      const float* wr = fw2 + j * 500;
      float acc = 0.f;
#pragma unroll
      for (int i = 0; i < 8; ++i) {
        int k = lane + 64 * i;
        float w = (k < 500) ? wr[k] : 0.f;
        acc = fmaf(hv[i], w, acc);
      }
#pragma unroll
      for (int off = 32; off > 0; off >>= 1) acc += __shfl_down(acc, off);
      lg[j] = acc + fb2[j];                  // valid at lane 0
    }
    if (lane == 0) {
      float m = lg[0];
#pragma unroll
      for (int j = 1; j < 10; ++j) m = fmaxf(m, lg[j]);
      float s = 0.f, e[10];
#pragma unroll
      for (int j = 0; j < 10; ++j) { e[j] = __expf(lg[j] - m); s += e[j]; }
      float inv = 1.f / s;
#pragma unroll
      for (int j = 0; j < 10; ++j) out[b * 10 + j] = e[j] * inv;
    }
  }
}

// ======================= R14 fallback kernels ==============================
__global__ __launch_bounds__(256) void prep_kernel(
    const float* __restrict__ w2, float* __restrict__ w2t,
    float* __restrict__ sums) {
  int idx = blockIdx.x * 256 + threadIdx.x;   // 134*256 = 34304
  if (idx < 32000) {
    int o = idx & 63, t = idx >> 6, k = t % 25, c = t / 25;
    w2t[idx] = (o < 50) ? w2[o * 500 + c * 25 + k] : 0.f;
  } else {
    int j = idx - 32000;
    if (j < NCOPY * 140) sums[j] = 0.f;
  }
}

__global__ __launch_bounds__(256) void adder1_bn_kernel(
    const float* __restrict__ x, const float* __restrict__ w1,
    float* __restrict__ out, float* __restrict__ sums) {
  __shared__ float csum[40];
  if (threadIdx.x < 40) csum[threadIdx.x] = 0.f;
  __syncthreads();
  int idx = blockIdx.x * 256 + threadIdx.x;
  int owc = idx % 3; int t = idx / 3;
  int oh  = t % 24;  t /= 24;
  int o   = t % 20;  int b = t / 20;
  const float* xb = x + b * 784;
  const float* wb = w1 + o * 25;
  float acc[8];
#pragma unroll
  for (int i = 0; i < 8; ++i) acc[i] = 0.f;
#pragma unroll
  for (int kh = 0; kh < 5; ++kh) {
    float xr[12];
    const float4* xp = (const float4*)(xb + (oh + kh) * 28 + owc * 8);
#pragma unroll
    for (int i = 0; i < 3; ++i) {
      float4 v = xp[i];
      xr[4*i] = v.x; xr[4*i+1] = v.y; xr[4*i+2] = v.z; xr[4*i+3] = v.w;
    }
    float wr[5];
#pragma unroll
    for (int i = 0; i < 5; ++i) wr[i] = wb[kh * 5 + i];
#pragma unroll
    for (int ow = 0; ow < 8; ++ow)
#pragma unroll
      for (int kw = 0; kw < 5; ++kw)
        acc[ow] += fabsf(xr[ow + kw] - wr[kw]);
  }
  float* op = out + (((size_t)b * 20 + o) * 24 + oh) * 24 + owc * 8;
  float4 s0 = { -acc[0], -acc[1], -acc[2], -acc[3] };
  float4 s1 = { -acc[4], -acc[5], -acc[6], -acc[7] };
  *(float4*)(op)     = s0;
  *(float4*)(op + 4) = s1;
  float s = 0.f, s2 = 0.f;
#pragma unroll
  for (int i = 0; i < 8; ++i) { s -= acc[i]; s2 += acc[i] * acc[i]; }
  atomicAdd(&csum[o * 2],     s);
  atomicAdd(&csum[o * 2 + 1], s2);
  __syncthreads();
  if (threadIdx.x < 40) {
    float v = csum[threadIdx.x];
    if (v != 0.f)
      atomicAdd(&sums[(blockIdx.x & (NCOPY - 1)) * 40 + threadIdx.x], v);
  }
}

__global__ __launch_bounds__(256) void adder2_bn_kernel(
    const float* __restrict__ h1, const float* __restrict__ sums1,
    const float* __restrict__ g1, const float* __restrict__ be1,
    const float* __restrict__ w2t,
    float* __restrict__ out, float* __restrict__ sums2) {
  __shared__ float lh[1440];
  __shared__ float sb[40];
  __shared__ float csum[100];
  const int tid = threadIdx.x;
  if (tid < 100) csum[tid] = 0.f;
  if (tid < 20) {
    float sm = 0.f, s2 = 0.f;
#pragma unroll
    for (int cp = 0; cp < NCOPY; ++cp) {
      sm += sums1[cp * 40 + 2 * tid];
      s2 += sums1[cp * 40 + 2 * tid + 1];
    }
    const float inv_n = 1.f / (B_N * 576);
    float mean = sm * inv_n;
    float var  = s2 * inv_n - mean * mean;
    float sc   = g1[tid] * rsqrtf(var + EPSBN);
    sb[2 * tid]     = sc;
    sb[2 * tid + 1] = be1[tid] - mean * sc;
  }
  __syncthreads();
  const int oq = blockIdx.x & 3;
  const int b  = blockIdx.x >> 2;
  {
    const float* hb = h1 + (size_t)b * 11520;
    for (int j = tid; j < 1440; j += 256) {
      int c = j / 72, rem = j - c * 72;
      int r = rem / 12, col = rem - r * 12;
      const float* hp = hb + (c * 24 + (4 * oq + 2 * r)) * 24 + 2 * col;
      float2 r0 = *(const float2*)(hp);
      float2 r1 = *(const float2*)(hp + 24);
      float sc = sb[2 * c], bi = sb[2 * c + 1];
      float v0 = fmaf(sc, r0.x, bi);
      float v1 = fmaf(sc, r0.y, bi);
      float v2 = fmaf(sc, r1.x, bi);
      float v3 = fmaf(sc, r1.y, bi);
      lh[j] = fmaxf(fmaxf(v0, v1), fmaxf(v2, v3));
    }
  }
  __syncthreads();
  const int o   = tid >> 2;
  const int q   = tid & 3;
  const int ohl = q >> 1;
  const int owh = q & 1;
  if (o < 50) {
    float acc[4];
#pragma unroll
    for (int i = 0; i < 4; ++i) acc[i] = 0.f;
    for (int c = 0; c < 20; ++c) {
      const float* lc = lh + c * 72 + owh * 4;
      const float* wc = w2t + c * 1600 + o;
#pragma unroll
      for (int kh = 0; kh < 5; ++kh) {
        float hr[8];
        const float* lp = lc + (ohl + kh) * 12;
        *(float4*)(hr)     = *(const float4*)(lp);
        *(float4*)(hr + 4) = *(const float4*)(lp + 4);
        float wr[5];
#pragma unroll
        for (int i = 0; i < 5; ++i) wr[i] = wc[(kh * 5 + i) * 64];
#pragma unroll
        for (int ow = 0; ow < 4; ++ow)
#pragma unroll
          for (int kw = 0; kw < 5; ++kw)
            acc[ow] += fabsf(hr[ow + kw] - wr[kw]);
      }
    }
    const int oh = 2 * oq + ohl;
    float4 st = { -acc[0], -acc[1], -acc[2], -acc[3] };
    *(float4*)(out + (((size_t)b * 50 + o) * 8 + oh) * 8 + owh * 4) = st;
    float s = 0.f, s2 = 0.f;
#pragma unroll
    for (int i = 0; i < 4; ++i) { s -= acc[i]; s2 += acc[i] * acc[i]; }
    atomicAdd(&csum[o * 2],     s);
    atomicAdd(&csum[o * 2 + 1], s2);
  }
  __syncthreads();
  if (tid < 100)
    atomicAdd(&sums2[(blockIdx.x & (NCOPY - 1)) * 100 + tid], csum[tid]);
}

__global__ __launch_bounds__(256) void bn_pool_t_kernel(
    const float* __restrict__ h, const float* __restrict__ sums,
    const float* __restrict__ gamma, const float* __restrict__ beta,
    float* __restrict__ featT4, float inv_n) {
  int idx = blockIdx.x * 256 + threadIdx.x;
  int pw = idx % 4; int t = idx / 4;
  int ph = t % 4;   t /= 4;
  int c  = t % 50;  int b = t / 50;
  float sm = 0.f, s2 = 0.f;
#pragma unroll
  for (int cp = 0; cp < NCOPY; ++cp) {
    sm += sums[cp * 100 + 2 * c];
    s2 += sums[cp * 100 + 2 * c + 1];
  }
  float mean = sm * inv_n;
  float var  = s2 * inv_n - mean * mean;
  float sc   = gamma[c] * rsqrtf(var + EPSBN);
  float bi   = beta[c] - mean * sc;
  const float* hp = h + ((b * 50 + c) * 8 + 2 * ph) * 8 + 2 * pw;
  float2 r0 = *(const float2*)(hp);
  float2 r1 = *(const float2*)(hp + 8);
  float v0 = fmaf(sc, r0.x, bi);
  float v1 = fmaf(sc, r0.y, bi);
  float v2 = fmaf(sc, r1.x, bi);
  float v3 = fmaf(sc, r1.y, bi);
  int kq = c * 4 + ph;
  featT4[(kq * 128 + b) * 4 + pw] = fmaxf(fmaxf(v0, v1), fmaxf(v2, v3));
}

__global__ __launch_bounds__(256) void fc1_kernel(
    const float* __restrict__ featT4, const float* __restrict__ w1,
    const float* __restrict__ b1, float* __restrict__ hid) {
  const int j = blockIdx.x;
  const int b = threadIdx.x & 127;
  const int khalf = threadIdx.x >> 7;
  const float* wr = w1 + j * 800;
  float a0 = 0.f, a1 = 0.f, a2 = 0.f, a3 = 0.f;
  int q0 = khalf * 100;
  for (int qi = q0; qi < q0 + 100; ++qi) {
    float4 f  = *(const float4*)(featT4 + (size_t)(qi * 128 + b) * 4);
    float4 w4 = *(const float4*)(wr + qi * 4);
    a0 = fmaf(f.x, w4.x, a0);
    a1 = fmaf(f.y, w4.y, a1);
    a2 = fmaf(f.z, w4.z, a2);
    a3 = fmaf(f.w, w4.w, a3);
  }
  __shared__ float part[256];
  part[threadIdx.x] = (a0 + a1) + (a2 + a3);
  __syncthreads();
  if (threadIdx.x < 128)
    hid[b * 512 + j] =
        fmaxf(b1[j] + part[threadIdx.x] + part[threadIdx.x + 128], 0.f);
}

__global__ __launch_bounds__(64) void fc2_softmax_kernel(
    const float* __restrict__ hid, const float* __restrict__ w2,
    const float* __restrict__ b2, float* __restrict__ out) {
  const int b = blockIdx.x, lane = threadIdx.x;
  const float* hb = hid + b * 512;
  __shared__ float logit[16];
  float hv[8];
#pragma unroll
  for (int i = 0; i < 8; ++i) {
    int k = lane + 64 * i;
    hv[i] = (k < 500) ? hb[k] : 0.f;
  }
  for (int j = 0; j < 10; ++j) {
    const float* wr = w2 + j * 500;
    float acc = 0.f;
#pragma unroll
    for (int i = 0; i < 8; ++i) {
      int k = lane + 64 * i;
      float w = (k < 500) ? wr[k] : 0.f;
      acc = fmaf(hv[i], w, acc);
    }
#pragma unroll
    for (int off = 32; off > 0; off >>= 1) acc += __shfl_down(acc, off);
    if (lane == 0) logit[j] = acc + b2[j];
  }
  __syncthreads();
  if (lane == 0) {
    float m = logit[0];
    for (int j = 1; j < 10; ++j) m = fmaxf(m, logit[j]);
    float s = 0.f, e[10];
    for (int j = 0; j < 10; ++j) { e[j] = __expf(logit[j] - m); s += e[j]; }
    float inv = 1.f / s;
    for (int j = 0; j < 10; ++j) out[b * 10 + j] = e[j] * inv;
  }
}

extern "C" void kernel_launch(void* const* d_in, const int* in_sizes, int n_in,
                              void* d_out, int out_size, void* d_ws, size_t ws_size,
                              hipStream_t stream) {
  const float* x   = (const float*)d_in[0];   // [128,1,28,28]
  const float* w1  = (const float*)d_in[1];   // [20,1,5,5]
  const float* g1  = (const float*)d_in[2];   // [20]
  const float* be1 = (const float*)d_in[3];   // [20]
  const float* w2  = (const float*)d_in[4];   // [50,20,5,5]
  const float* g2  = (const float*)d_in[5];   // [50]
  const float* be2 = (const float*)d_in[6];   // [50]
  const float* fw1 = (const float*)d_in[7];   // [500,800]
  const float* fb1 = (const float*)d_in[8];   // [500]
  const float* fw2 = (const float*)d_in[9];   // [10,500]
  const float* fb2 = (const float*)d_in[10];  // [10]
  float* outp = (float*)d_out;
  float* ws   = (float*)d_ws;

  // zero the 4 one-shot barrier counters (512B), then launch cooperatively
  hipError_t err = hipMemsetAsync((void*)(ws + 2600000), 0, 512, stream);
  if (err == hipSuccess) {
    void* args[13] = {(void*)&x,   (void*)&w1,  (void*)&g1,  (void*)&be1,
                      (void*)&w2,  (void*)&g2,  (void*)&be2, (void*)&fw1,
                      (void*)&fb1, (void*)&fw2, (void*)&fb2, (void*)&outp,
                      (void*)&ws};
    err = hipLaunchCooperativeKernel((const void*)mega_kernel, dim3(NBLK),
                                     dim3(256), args, 0, stream);
  }

  if (err != hipSuccess) {
    // ---- fallback: proven R14 6-dispatch path (own ws sub-layout) ----
    float* h1     = ws;               // 1,474,560
    float* sums1  = ws + 1843200;     // 640
    float* sums2  = ws + 1843840;     // 1600
    float* w2t    = ws + 1845504;     // 32,000
    float* h2     = ws + 1900000;     // 409,600
    float* featT4 = ws + 2310000;     // 102,400
    float* hid    = ws + 2420000;     // 65,536
    prep_kernel<<<134, 256, 0, stream>>>(w2, w2t, sums1);
    adder1_bn_kernel<<<720, 256, 0, stream>>>(x, w1, h1, sums1);
    adder2_bn_kernel<<<512, 256, 0, stream>>>(h1, sums1, g1, be1, w2t, h2, sums2);
    bn_pool_t_kernel<<<400, 256, 0, stream>>>(h2, sums2, g2, be2, featT4,
                                              1.f / (B_N * 64));
    fc1_kernel<<<500, 256, 0, stream>>>(featT4, fw1, fb1, hid);
    fc2_softmax_kernel<<<128, 64, 0, stream>>>(hid, fw2, fb2, outp);
  }
}

// Round 8
// 142.804 us; speedup vs baseline: 4.9350x; 3.5396x over previous
//
#include <hip/hip_runtime.h>
#include <math.h>

// ---------------------------------------------------------------------------
// AdderNet LeNet forward. R22: 4-dispatch path (from R14's 6).
// Mega-kernel direction abandoned: coop launch = correct but not
// graph-capturable (R20); normal launch = co-residency unsafe (R21 garbage);
// threadfence barriers = 90us each (R18).
// Fusions (all boundary-coherent, no atomics on globals, no zero-init):
//  - prep gone: adder1 writes deterministic sums1p[40][720] (transposed);
//    adder2 reduces it per-block (float4 contiguous, R20-verified numerics);
//    w2 read directly (R20-verified, same accumulation order as w2t).
//  - bn_pool_t gone: pool commutes with BN (gamma2=1>0); adder2 pools its own
//    2x2 windows in-register (shfl_xor partner row) -> pooledT4 pre-BN;
//    h2 never materialized. fc1 folds BN2: per-block sums2p[100][512]
//    reduction -> sb, then fmaf(sc,f,bi) inside k-loop (bit-identical op
//    order to R14's featT4 path).
// ---------------------------------------------------------------------------

#define B_N 128
#define EPSBN 1e-5f

// ---- K1: adder1 + BN1 per-block partials -> sums1p[40][720] ---------------
__global__ __launch_bounds__(256) void adder1_bn_kernel(
    const float* __restrict__ x, const float* __restrict__ w1,
    float* __restrict__ h1, float* __restrict__ sums1p) {
  __shared__ float csum[40];
  if (threadIdx.x < 40) csum[threadIdx.x] = 0.f;
  __syncthreads();
  int idx = blockIdx.x * 256 + threadIdx.x;   // 184320 = 720*256
  int owc = idx % 3; int t = idx / 3;
  int oh  = t % 24;  t /= 24;
  int o   = t % 20;  int b = t / 20;
  const float* xb = x + b * 784;
  const float* wb = w1 + o * 25;
  float acc[8];
#pragma unroll
  for (int i = 0; i < 8; ++i) acc[i] = 0.f;
#pragma unroll
  for (int kh = 0; kh < 5; ++kh) {
    float xr[12];
    const float4* xp = (const float4*)(xb + (oh + kh) * 28 + owc * 8);
#pragma unroll
    for (int i = 0; i < 3; ++i) {
      float4 v = xp[i];
      xr[4*i] = v.x; xr[4*i+1] = v.y; xr[4*i+2] = v.z; xr[4*i+3] = v.w;
    }
    float wr[5];
#pragma unroll
    for (int i = 0; i < 5; ++i) wr[i] = wb[kh * 5 + i];
#pragma unroll
    for (int ow = 0; ow < 8; ++ow)
#pragma unroll
      for (int kw = 0; kw < 5; ++kw)
        acc[ow] += fabsf(xr[ow + kw] - wr[kw]);
  }
  float* op = h1 + (((size_t)b * 20 + o) * 24 + oh) * 24 + owc * 8;
  float4 s0 = { -acc[0], -acc[1], -acc[2], -acc[3] };
  float4 s1 = { -acc[4], -acc[5], -acc[6], -acc[7] };
  *(float4*)(op)     = s0;
  *(float4*)(op + 4) = s1;
  float s = 0.f, s2 = 0.f;
#pragma unroll
  for (int i = 0; i < 8; ++i) { s -= acc[i]; s2 += acc[i] * acc[i]; }
  atomicAdd(&csum[o * 2],     s);
  atomicAdd(&csum[o * 2 + 1], s2);
  __syncthreads();
  if (threadIdx.x < 40)
    sums1p[threadIdx.x * 720 + blockIdx.x] = csum[threadIdx.x];
}

// ---- K2: BN1 finalize + stage/pool + adder2 (w2 direct) + in-reg 2x2 pool -
// 512 blocks = 128 b x 4 oq. Output: pooledT4[(o*4+oq)*128+b][4] (pre-BN2),
// sums2p[100][512] per-block partials.
__global__ __launch_bounds__(256) void adder2_pool_kernel(
    const float* __restrict__ h1, const float* __restrict__ sums1p,
    const float* __restrict__ g1, const float* __restrict__ be1,
    const float* __restrict__ w2,
    float* __restrict__ pooledT4, float* __restrict__ sums2p) {
  __shared__ float lh[1440];    // staging; [0..239] reused as reduction scratch
  __shared__ float sb[40];
  __shared__ float csum[100];
  const int tid = threadIdx.x;
  const int bk  = blockIdx.x;

  // BN1 finalize: reduce sums1p[40][720] (contiguous float4 chunks)
  {
    if (tid < 240) {                       // 40 stats x 6 chunks of 120
      int sv = tid / 6, ch = tid % 6;
      const float4* sp = (const float4*)(sums1p + sv * 720 + ch * 120);
      float p = 0.f;
#pragma unroll
      for (int i = 0; i < 30; ++i) {
        float4 v = sp[i];
        p += (v.x + v.y) + (v.z + v.w);
      }
      lh[tid] = p;
    }
    if (tid < 100) csum[tid] = 0.f;
    __syncthreads();
    if (tid < 40) {
      float sm = 0.f;
#pragma unroll
      for (int i = 0; i < 6; ++i) sm += lh[tid * 6 + i];
      lh[1200 + tid] = sm;
    }
    __syncthreads();
    if (tid < 20) {
      const float inv_n = 1.f / (B_N * 576);
      float mean = lh[1200 + 2 * tid] * inv_n;
      float var  = lh[1200 + 2 * tid + 1] * inv_n - mean * mean;
      float sc   = g1[tid] * rsqrtf(var + EPSBN);
      sb[2 * tid]     = sc;
      sb[2 * tid + 1] = be1[tid] - mean * sc;
    }
    __syncthreads();
  }
  const int oq = bk & 3;
  const int b  = bk >> 2;
  // stage: lh[c][6 rows][12] = BN1+pool of h1 rows 4oq..4oq+5
  {
    const float* hb = h1 + (size_t)b * 11520;
    for (int j = tid; j < 1440; j += 256) {
      int c = j / 72, rem = j - c * 72;
      int r = rem / 12, col = rem - r * 12;
      const float* hp = hb + (c * 24 + (4 * oq + 2 * r)) * 24 + 2 * col;
      float2 r0 = *(const float2*)(hp);
      float2 r1 = *(const float2*)(hp + 24);
      float sc = sb[2 * c], bi = sb[2 * c + 1];
      float v0 = fmaf(sc, r0.x, bi);
      float v1 = fmaf(sc, r0.y, bi);
      float v2 = fmaf(sc, r1.x, bi);
      float v3 = fmaf(sc, r1.y, bi);
      lh[j] = fmaxf(fmaxf(v0, v1), fmaxf(v2, v3));
    }
  }
  __syncthreads();
  {
    const int o   = tid >> 2;
    const int q   = tid & 3;
    const int ohl = q >> 1;
    const int owh = q & 1;
    float m0 = 0.f, m1 = 0.f;
    bool active = (o < 50);
    if (active) {
      float acc[4];
#pragma unroll
      for (int i = 0; i < 4; ++i) acc[i] = 0.f;
      for (int c = 0; c < 20; ++c) {
        const float* lc = lh + c * 72 + owh * 4;
        const float* wc = w2 + o * 500 + c * 25;
#pragma unroll
        for (int kh = 0; kh < 5; ++kh) {
          float hr[8];
          const float* lp = lc + (ohl + kh) * 12;
          *(float4*)(hr)     = *(const float4*)(lp);
          *(float4*)(hr + 4) = *(const float4*)(lp + 4);
          float wr[5];
#pragma unroll
          for (int i = 0; i < 5; ++i) wr[i] = wc[kh * 5 + i];
#pragma unroll
          for (int ow = 0; ow < 4; ++ow)
#pragma unroll
            for (int kw = 0; kw < 5; ++kw)
              acc[ow] += fabsf(hr[ow + kw] - wr[kw]);
        }
      }
      // BN2 partials over full (pre-pool) h2 values v_i = -acc[i]
      float s = 0.f, s2 = 0.f;
#pragma unroll
      for (int i = 0; i < 4; ++i) { s -= acc[i]; s2 += acc[i] * acc[i]; }
      atomicAdd(&csum[o * 2],     s);
      atomicAdd(&csum[o * 2 + 1], s2);
      // in-register 2x2 pool (pre-BN; BN applied in fc1, commutes since sc>0)
      m0 = fmaxf(-acc[0], -acc[1]);       // col pair (2*owh*2 + 0,1)
      m1 = fmaxf(-acc[2], -acc[3]);       // col pair (+2,+3)
    }
    // partner row (ohl^1) lives at lane tid^2 in the same wave
    float p0 = fmaxf(m0, __shfl_xor(m0, 2));
    float p1 = fmaxf(m1, __shfl_xor(m1, 2));
    if (active && ohl == 0) {
      int kq = o * 4 + oq;                // ph == oq
      float2 pv = { p0, p1 };
      *(float2*)(pooledT4 + ((size_t)kq * 128 + b) * 4 + owh * 2) = pv;
    }
  }
  __syncthreads();
  if (tid < 100) sums2p[tid * 512 + bk] = csum[tid];
}

// ---- K3: BN2 finalize + fc1 (BN folded) + relu ----------------------------
__global__ __launch_bounds__(256) void fc1_bn_kernel(
    const float* __restrict__ pooledT4, const float* __restrict__ sums2p,
    const float* __restrict__ g2, const float* __restrict__ be2,
    const float* __restrict__ w1, const float* __restrict__ b1,
    float* __restrict__ hid) {
  __shared__ float red[200];
  __shared__ float sb[100];
  __shared__ float part[256];
  const int tid = threadIdx.x;
  // BN2 finalize: reduce sums2p[100][512]
  {
    if (tid < 200) {                      // 100 stats x 2 halves of 256
      int sv = tid >> 1, hh = tid & 1;
      const float4* sp = (const float4*)(sums2p + sv * 512 + hh * 256);
      float p = 0.f;
#pragma unroll
      for (int i = 0; i < 64; ++i) {
        float4 v = sp[i];
        p += (v.x + v.y) + (v.z + v.w);
      }
      red[tid] = p;
    }
    __syncthreads();
    if (tid < 50) {
      const float inv_n = 1.f / (B_N * 64);
      float sm = red[4 * tid]     + red[4 * tid + 1];
      float s2 = red[4 * tid + 2] + red[4 * tid + 3];
      float mean = sm * inv_n;
      float var  = s2 * inv_n - mean * mean;
      float sc   = g2[tid] * rsqrtf(var + EPSBN);
      sb[2 * tid]     = sc;
      sb[2 * tid + 1] = be2[tid] - mean * sc;
    }
    __syncthreads();
  }
  const int j = blockIdx.x;
  const int b = tid & 127;
  const int khalf = tid >> 7;
  const float* wr = w1 + j * 800;
  float a0 = 0.f, a1 = 0.f, a2 = 0.f, a3 = 0.f;
  int q0 = khalf * 100;
  for (int qi = q0; qi < q0 + 100; ++qi) {
    float4 f  = *(const float4*)(pooledT4 + (size_t)(qi * 128 + b) * 4);
    float4 w4 = *(const float4*)(wr + qi * 4);   // wave-uniform
    int c = qi >> 2;
    float sc = sb[2 * c], bi = sb[2 * c + 1];    // uniform LDS broadcast
    a0 = fmaf(fmaf(sc, f.x, bi), w4.x, a0);
    a1 = fmaf(fmaf(sc, f.y, bi), w4.y, a1);
    a2 = fmaf(fmaf(sc, f.z, bi), w4.z, a2);
    a3 = fmaf(fmaf(sc, f.w, bi), w4.w, a3);
  }
  part[tid] = (a0 + a1) + (a2 + a3);
  __syncthreads();
  if (tid < 128)
    hid[b * 512 + j] = fmaxf(b1[j] + part[tid] + part[tid + 128], 0.f);
}

// ---- K4: fc2 + bias + softmax ---------------------------------------------
__global__ __launch_bounds__(64) void fc2_softmax_kernel(
    const float* __restrict__ hid, const float* __restrict__ w2,
    const float* __restrict__ b2, float* __restrict__ out) {
  const int b = blockIdx.x, lane = threadIdx.x;
  const float* hb = hid + b * 512;
  __shared__ float logit[16];
  float hv[8];
#pragma unroll
  for (int i = 0; i < 8; ++i) {
    int k = lane + 64 * i;
    hv[i] = (k < 500) ? hb[k] : 0.f;
  }
  for (int j = 0; j < 10; ++j) {
    const float* wr = w2 + j * 500;
    float acc = 0.f;
#pragma unroll
    for (int i = 0; i < 8; ++i) {
      int k = lane + 64 * i;
      float w = (k < 500) ? wr[k] : 0.f;
      acc = fmaf(hv[i], w, acc);
    }
#pragma unroll
    for (int off = 32; off > 0; off >>= 1) acc += __shfl_down(acc, off);
    if (lane == 0) logit[j] = acc + b2[j];
  }
  __syncthreads();
  if (lane == 0) {
    float m = logit[0];
    for (int j = 1; j < 10; ++j) m = fmaxf(m, logit[j]);
    float s = 0.f, e[10];
    for (int j = 0; j < 10; ++j) { e[j] = __expf(logit[j] - m); s += e[j]; }
    float inv = 1.f / s;
    for (int j = 0; j < 10; ++j) out[b * 10 + j] = e[j] * inv;
  }
}

extern "C" void kernel_launch(void* const* d_in, const int* in_sizes, int n_in,
                              void* d_out, int out_size, void* d_ws, size_t ws_size,
                              hipStream_t stream) {
  const float* x   = (const float*)d_in[0];   // [128,1,28,28]
  const float* w1  = (const float*)d_in[1];   // [20,1,5,5]
  const float* g1  = (const float*)d_in[2];   // [20]
  const float* be1 = (const float*)d_in[3];   // [20]
  const float* w2  = (const float*)d_in[4];   // [50,20,5,5]
  const float* g2  = (const float*)d_in[5];   // [50]
  const float* be2 = (const float*)d_in[6];   // [50]
  const float* fw1 = (const float*)d_in[7];   // [500,800]
  const float* fb1 = (const float*)d_in[8];   // [500]
  const float* fw2 = (const float*)d_in[9];   // [10,500]
  const float* fb2 = (const float*)d_in[10];  // [10]
  float* outp = (float*)d_out;
  float* ws   = (float*)d_ws;

  // workspace layout (floats) — all disjoint, no zero-init needed
  float* h1       = ws;               // 1,474,560   [128][20][24][24]
  float* sums1p   = ws + 1480000;     // 28,800      [40][720]
  float* sums2p   = ws + 1520000;     // 51,200      [100][512]
  float* pooledT4 = ws + 1580000;     // 102,400     [200][128][4] (pre-BN2)
  float* hid      = ws + 1690000;     // 65,536      [128][512]

  adder1_bn_kernel<<<720, 256, 0, stream>>>(x, w1, h1, sums1p);
  adder2_pool_kernel<<<512, 256, 0, stream>>>(h1, sums1p, g1, be1, w2,
                                              pooledT4, sums2p);
  fc1_bn_kernel<<<500, 256, 0, stream>>>(pooledT4, sums2p, g2, be2,
                                         fw1, fb1, hid);
  fc2_softmax_kernel<<<128, 64, 0, stream>>>(hid, fw2, fb2, outp);
}